// Round 1
// baseline (344.534 us; speedup 1.0000x reference)
//
#include <hip/hip_runtime.h>
#include <math.h>

// Problem constants (B=2, N=M=2048, d_model=1024, m_bits=32, d_head=64)
#define DM 1024
#define NB 2048
#define MBITS 32
#define DH 64

typedef __attribute__((ext_vector_type(4))) float floatx4;
typedef __attribute__((ext_vector_type(8))) short shortx8;

__device__ __forceinline__ unsigned short f32_to_bf16(float f) {
    union { float f; unsigned u; } v; v.f = f;
    unsigned r = v.u + 0x7FFF + ((v.u >> 16) & 1);   // RNE
    return (unsigned short)(r >> 16);
}

// hi/lo truncation split of two f32 -> packed bf16x2 (el0 low, el1 high)
__device__ __forceinline__ void split2(float x0, float x1, unsigned& hp, unsigned& lp) {
    union { float f; unsigned u; } a, b; a.f = x0; b.f = x1;
    unsigned h0 = a.u & 0xFFFF0000u, h1 = b.u & 0xFFFF0000u;
    union { unsigned u; float f; } hf0, hf1; hf0.u = h0; hf1.u = h1;
    union { float f; unsigned u; } c, d;
    c.f = x0 - hf0.f;   // exact (Sterbenz)
    d.f = x1 - hf1.f;
    hp = (h0 >> 16) | h1;
    lp = (c.u >> 16) | (d.u & 0xFFFF0000u);
}

// ---------------------------------------------------------------------------
// W prep: pack Wq/Wk/Wv into MFMA B-frag order, bf16 hi/lo. (layout verified r3)
// ---------------------------------------------------------------------------
__global__ __launch_bounds__(256) void wprep_kernel(
    const float* __restrict__ Wq, const float* __restrict__ Wk,
    const float* __restrict__ Wv, unsigned short* __restrict__ Wf)
{
    int wv = blockIdx.x * 4 + (threadIdx.x >> 6);
    int l  = threadIdx.x & 63;
    const float* W; int C, kc32, ct;
    if (wv < 64)       { W = Wq; C = 32; kc32 = wv >> 1;  ct = wv & 1; }
    else if (wv < 128) { W = Wk; C = 32; int z = wv - 64;  kc32 = z >> 1; ct = z & 1; }
    else               { W = Wv; C = 64; int z = wv - 128; kc32 = z >> 2; ct = z & 3; }
    int k0 = kc32 * 32 + (l >> 4) * 8;
    int c  = ct * 16 + (l & 15);
    float x[8];
    #pragma unroll
    for (int j = 0; j < 8; ++j) x[j] = W[(size_t)(k0 + j) * C + c];
    unsigned hp[4], lp[4];
    #pragma unroll
    for (int j2 = 0; j2 < 4; ++j2) split2(x[2 * j2], x[2 * j2 + 1], hp[j2], lp[j2]);
    uint4 hv; hv.x = hp[0]; hv.y = hp[1]; hv.z = hp[2]; hv.w = hp[3];
    uint4 lv; lv.x = lp[0]; lv.y = lp[1]; lv.z = lp[2]; lv.w = lp[3];
    *(uint4*)&Wf[(size_t)wv * 1024 + l * 8]       = hv;
    *(uint4*)&Wf[(size_t)wv * 1024 + 512 + l * 8] = lv;
}

// ---------------------------------------------------------------------------
// Projections: register-direct A-frags, split-K x4 across 4 waves, LDS
// cross-wave reduction. grid 768 x 256. (unchanged, verified)
// ---------------------------------------------------------------------------
__global__ __launch_bounds__(256) void proj_mfma2_kernel(
    const float* __restrict__ Q, const float* __restrict__ K, const float* __restrict__ V,
    const unsigned short* __restrict__ Wf,
    float* __restrict__ Qt, float* __restrict__ Kt, unsigned short* __restrict__ VpT)
{
    __shared__ float red[4][64][16];   // [wave][lane][ct*4+r]  = 16 KB

    int gb = blockIdx.x;
    int job = gb >> 8, tile = gb & 255;
    int r0 = tile * 16;
    const float* X = (job == 0) ? Q : (job == 1) ? K : V;
    int ntct  = (job == 2) ? 4 : 2;
    int pbase = job << 6;
    int t = threadIdx.x, w = t >> 6, l = t & 63;
    int lrow = l & 15, lq = l >> 4;

    const float* xrow = &X[(size_t)(r0 + lrow) * DM + w * 256 + lq * 8];

    floatx4 acc[4];
    #pragma unroll
    for (int i = 0; i < 4; ++i) acc[i] = (floatx4){0.f, 0.f, 0.f, 0.f};

    #pragma unroll
    for (int s = 0; s < 8; ++s) {
        floatx4 g0 = *(const floatx4*)(xrow + s * 32);
        floatx4 g1 = *(const floatx4*)(xrow + s * 32 + 4);
        union { unsigned u[4]; shortx8 v; } ahi, alo;
        split2(g0.x, g0.y, ahi.u[0], alo.u[0]);
        split2(g0.z, g0.w, ahi.u[1], alo.u[1]);
        split2(g1.x, g1.y, ahi.u[2], alo.u[2]);
        split2(g1.z, g1.w, ahi.u[3], alo.u[3]);
        int kc32 = w * 8 + s;
        #pragma unroll
        for (int ct = 0; ct < 4; ++ct) {
            if (ct >= ntct) break;
            int p = pbase + kc32 * ntct + ct;
            const unsigned short* wp = &Wf[(size_t)p * 1024 + l * 8];
            shortx8 bhi = *(const shortx8*)wp;
            shortx8 blo = *(const shortx8*)(wp + 512);
            acc[ct] = __builtin_amdgcn_mfma_f32_16x16x32_bf16(ahi.v, bhi, acc[ct], 0, 0, 0);
            acc[ct] = __builtin_amdgcn_mfma_f32_16x16x32_bf16(ahi.v, blo, acc[ct], 0, 0, 0);
            acc[ct] = __builtin_amdgcn_mfma_f32_16x16x32_bf16(alo.v, bhi, acc[ct], 0, 0, 0);
        }
    }

    #pragma unroll
    for (int ct = 0; ct < 4; ++ct) {
        if (ct >= ntct) break;
        #pragma unroll
        for (int r = 0; r < 4; ++r) red[w][l][ct * 4 + r] = acc[ct][r];
    }
    __syncthreads();

    int row = r0 + lq * 4 + w;
    if (job < 2) {
        float* Y = (job == 0) ? Qt : Kt;
        #pragma unroll
        for (int ct = 0; ct < 2; ++ct) {
            float v = red[0][l][ct * 4 + w] + red[1][l][ct * 4 + w]
                    + red[2][l][ct * 4 + w] + red[3][l][ct * 4 + w];
            Y[(size_t)row * MBITS + ct * 16 + lrow] = v;
        }
    } else {
        int b = row >> 11, j = row & 2047;
        #pragma unroll
        for (int ct = 0; ct < 4; ++ct) {
            float v = red[0][l][ct * 4 + w] + red[1][l][ct * 4 + w]
                    + red[2][l][ct * 4 + w] + red[3][l][ct * 4 + w];
            VpT[(size_t)b * (DH * NB) + (size_t)(ct * 16 + lrow) * NB + j] = f32_to_bf16(v);
        }
    }
}

// ---------------------------------------------------------------------------
// Fused score + softmax + attn-write + PV pass.
// Grid (128, 2) x 1024 threads (16 waves), 1 block/CU, 148 KB LDS.
// Per block: rows [i0, i0+16), all 2048 j, one batch.
// Phase 1: tropical min-plus straight from L2 (Qt row slab is 2 KB -> L1;
//   Kt is 256 KB/batch -> L2). Wave w: rows (w&1)*8+r, j in [(w>>1)*256,+256),
//   lane covers 4 consecutive j. m[8][4] in regs; no barriers in k-loop.
//   e = exp2(c2*m) -> bf16 -> Elds[16][2056] (+8 pad => conflict-free MFMA A
//   reads: row stride 4112 B = 257 quads == 1 mod 8).
// Phase 2: V tiles double-buffered (T14 issue-early/write-late), MFMA
//   16x16x32 on unnormalized e, split-k over 4 wave-groups, LDS reduction,
//   direct out write (no atomics, no memset). attn written normalized,
//   coalesced 1 KB/wave.
// ---------------------------------------------------------------------------
__global__ __launch_bounds__(1024) void fused_score_out_kernel(
    const float* __restrict__ Qt, const float* __restrict__ Kt,
    const unsigned short* __restrict__ VpT, const float* __restrict__ temp,
    float* __restrict__ outp, float* __restrict__ attn)
{
    __shared__ unsigned short Elds[16][2056];    // 65792 B  unnormalized e (bf16)
    __shared__ unsigned short Vsb[2][64][256];   // 65536 B  V tile double buffer
    __shared__ float redsum[16][8];              //   512 B  per-wave row sums
    __shared__ float inv_s[16];                  //    64 B
    __shared__ float redC[16][64][4];            // 16384 B  cross-wave C reduce

    const int b  = blockIdx.y;
    const int i0 = blockIdx.x * 16;
    const int t  = threadIdx.x;
    const int w  = t >> 6, l = t & 63;
    const int wr = w & 1;              // row half (rows wr*8 .. wr*8+7)
    const int wj = w >> 1;             // j octant
    const int jb = wj * 256 + l * 4;   // first of this lane's 4 j columns

    const float tv = temp[0];
    const float c2 = -(1.0f / log1pf(__expf(tv))) * 1.44269504088896340736f;

    const float* Krow = &Kt[(size_t)(b * NB + jb) * MBITS];
    const float* Qrow = &Qt[(size_t)(b * NB + i0 + wr * 8) * MBITS];

    // ---- Phase 1: tropical min-plus ------------------------------------
    float m[8][4];
    #pragma unroll
    for (int r = 0; r < 8; ++r)
        #pragma unroll
        for (int jj = 0; jj < 4; ++jj) m[r][jj] = 1e30f;

    #pragma unroll
    for (int k4 = 0; k4 < 8; ++k4) {
        floatx4 kk[4];
        #pragma unroll
        for (int jj = 0; jj < 4; ++jj)
            kk[jj] = *(const floatx4*)&Krow[jj * MBITS + k4 * 4];
        #pragma unroll
        for (int r = 0; r < 8; ++r) {
            floatx4 q = *(const floatx4*)&Qrow[r * MBITS + k4 * 4];  // wave-uniform, L1-hot
            #pragma unroll
            for (int jj = 0; jj < 4; ++jj) {
                float a0 = q.x + kk[jj].x;
                float a1 = q.y + kk[jj].y;
                float a2 = q.z + kk[jj].z;
                float a3 = q.w + kk[jj].w;
                m[r][jj] = fminf(fminf(m[r][jj], fminf(a0, a1)), fminf(a2, a3));
            }
        }
    }

    // e = exp2(c2*m); write bf16 to Elds; per-row wave-reduced sums
    #pragma unroll
    for (int r = 0; r < 8; ++r) {
        float e0 = exp2f(c2 * m[r][0]);
        float e1 = exp2f(c2 * m[r][1]);
        float e2 = exp2f(c2 * m[r][2]);
        float e3 = exp2f(c2 * m[r][3]);
        uint2 pk;
        pk.x = (unsigned)f32_to_bf16(e0) | ((unsigned)f32_to_bf16(e1) << 16);
        pk.y = (unsigned)f32_to_bf16(e2) | ((unsigned)f32_to_bf16(e3) << 16);
        *(uint2*)&Elds[wr * 8 + r][jb] = pk;
        float s = (e0 + e1) + (e2 + e3);
        #pragma unroll
        for (int off = 1; off < 64; off <<= 1) s += __shfl_xor(s, off, 64);
        if (l == 0) redsum[w][r] = s;
    }
    __syncthreads();

    // inv_s: row i gets contributions from waves w with (w&1)==(i>>3)
    if (t < 16) {
        float s = 0.f;
        #pragma unroll
        for (int g = 0; g < 8; ++g) s += redsum[(t >> 3) + 2 * g][t & 7];
        inv_s[t] = 1.0f / s;
    }

    // stage V chunk 0 into buffer 0 (same layout/swizzle as verified kernel)
    const int sh = t >> 5, sc = t & 31;
    {
        uint4 g0 = *(const uint4*)&VpT[(size_t)b * (DH * NB) + (size_t)sh * NB + sc * 8];
        uint4 g1 = *(const uint4*)&VpT[(size_t)b * (DH * NB) + (size_t)(sh + 32) * NB + sc * 8];
        *(uint4*)&Vsb[0][sh][(sc ^ (sh & 31)) * 8]             = g0;
        *(uint4*)&Vsb[0][sh + 32][(sc ^ ((sh + 32) & 31)) * 8] = g1;
    }
    __syncthreads();

    // ---- Phase 2: normalize + attn write + PV MFMA ----------------------
    const int mrow = l & 15, q4 = l >> 4;
    const int hh  = (w & 3) * 16 + mrow;   // output head column this wave owns
    const int kg  = w >> 2;                // k-split group (0..3)
    const int vsw = hh & 31;
    const float iv = inv_s[w];             // this wave normalizes attn row w
    floatx4 acc = {0.f, 0.f, 0.f, 0.f};
    int pb = 0;

    for (int jc2 = 0; jc2 < 8; ++jc2) {
        // T14: issue next-tile loads early, write to LDS late
        uint4 g0, g1;
        if (jc2 < 7) {
            g0 = *(const uint4*)&VpT[(size_t)b * (DH * NB) + (size_t)sh * NB + (jc2 + 1) * 256 + sc * 8];
            g1 = *(const uint4*)&VpT[(size_t)b * (DH * NB) + (size_t)(sh + 32) * NB + (jc2 + 1) * 256 + sc * 8];
        }
        // MFMA: this wave's 2 k-steps of this chunk (accumulate across chunks)
        #pragma unroll
        for (int t2 = 0; t2 < 2; ++t2) {
            int ks = kg * 2 + t2;
            shortx8 a = *(const shortx8*)&Elds[mrow][jc2 * 256 + ks * 32 + q4 * 8];
            int c = ks * 4 + q4;
            shortx8 bf = *(const shortx8*)&Vsb[pb][hh][(c ^ vsw) * 8];
            acc = __builtin_amdgcn_mfma_f32_16x16x32_bf16(a, bf, acc, 0, 0, 0);
        }
        // normalize + write attn (wave w owns row w; 1 KB contiguous per wave)
        {
            uint2 pk = *(const uint2*)&Elds[w][jc2 * 256 + l * 4];
            union { unsigned u; float f; } x0, x1, x2, x3;
            x0.u = pk.x << 16; x1.u = pk.x & 0xFFFF0000u;
            x2.u = pk.y << 16; x3.u = pk.y & 0xFFFF0000u;
            floatx4 o;
            o.x = x0.f * iv; o.y = x1.f * iv; o.z = x2.f * iv; o.w = x3.f * iv;
            *(floatx4*)&attn[(size_t)(b * NB + i0 + w) * 2048 + jc2 * 256 + l * 4] = o;
        }
        if (jc2 < 7) {
            *(uint4*)&Vsb[pb ^ 1][sh][(sc ^ (sh & 31)) * 8]             = g0;
            *(uint4*)&Vsb[pb ^ 1][sh + 32][(sc ^ ((sh + 32) & 31)) * 8] = g1;
        }
        __syncthreads();
        pb ^= 1;
    }

    // cross-wave reduce the 4 k-split partial accumulators, write out
    *(floatx4*)&redC[w][l][0] = acc;
    __syncthreads();
    if (w < 4) {
        floatx4 v0 = *(const floatx4*)&redC[w][l][0];
        floatx4 v1 = *(const floatx4*)&redC[w + 4][l][0];
        floatx4 v2 = *(const floatx4*)&redC[w + 8][l][0];
        floatx4 v3 = *(const floatx4*)&redC[w + 12][l][0];
        #pragma unroll
        for (int r = 0; r < 4; ++r) {
            int irow = q4 * 4 + r;
            float v = (v0[r] + v1[r]) + (v2[r] + v3[r]);
            outp[(size_t)(b * NB + i0 + irow) * DH + w * 16 + mrow] = v * inv_s[irow];
        }
    }
}

// ---------------------------------------------------------------------------
extern "C" void kernel_launch(void* const* d_in, const int* in_sizes, int n_in,
                              void* d_out, int out_size, void* d_ws, size_t ws_size,
                              hipStream_t stream) {
    (void)in_sizes; (void)n_in; (void)out_size; (void)ws_size;
    const float* Q    = (const float*)d_in[0];
    const float* K    = (const float*)d_in[1];
    const float* V    = (const float*)d_in[2];
    const float* Wq   = (const float*)d_in[3];
    const float* Wk   = (const float*)d_in[4];
    const float* Wv   = (const float*)d_in[5];
    const float* temp = (const float*)d_in[6];

    float* outp = (float*)d_out;                 // [2][2048][64]
    float* attn = outp + 2 * 2048 * 64;          // [2][2048][2048]

    char* ws = (char*)d_ws;
    float*          Qt  = (float*)(ws);                       // 512 KB
    float*          Kt  = (float*)(ws + 524288);              // 512 KB
    unsigned short* Wf  = (unsigned short*)(ws + 1179648);    // 512 KB
    unsigned short* VpT = (unsigned short*)(ws + 1703936);    // 512 KB

    wprep_kernel<<<64, 256, 0, stream>>>(Wq, Wk, Wv, Wf);
    proj_mfma2_kernel<<<768, 256, 0, stream>>>(Q, K, V, Wf, Qt, Kt, VpT);
    fused_score_out_kernel<<<dim3(128, 2), 1024, 0, stream>>>(Qt, Kt, VpT, temp, outp, attn);
}

// Round 3
// 340.773 us; speedup vs baseline: 1.0110x; 1.0110x over previous
//
#include <hip/hip_runtime.h>
#include <math.h>

// Problem constants (B=2, N=M=2048, d_model=1024, m_bits=32, d_head=64)
#define DM 1024
#define NB 2048
#define MBITS 32
#define DH 64

typedef __attribute__((ext_vector_type(4))) float floatx4;
typedef __attribute__((ext_vector_type(8))) short shortx8;

__device__ __forceinline__ unsigned short f32_to_bf16(float f) {
    union { float f; unsigned u; } v; v.f = f;
    unsigned r = v.u + 0x7FFF + ((v.u >> 16) & 1);   // RNE
    return (unsigned short)(r >> 16);
}

// hi/lo truncation split of two f32 -> packed bf16x2 (el0 low, el1 high)
__device__ __forceinline__ void split2(float x0, float x1, unsigned& hp, unsigned& lp) {
    union { float f; unsigned u; } a, b; a.f = x0; b.f = x1;
    unsigned h0 = a.u & 0xFFFF0000u, h1 = b.u & 0xFFFF0000u;
    union { unsigned u; float f; } hf0, hf1; hf0.u = h0; hf1.u = h1;
    union { float f; unsigned u; } c, d;
    c.f = x0 - hf0.f;   // exact (Sterbenz)
    d.f = x1 - hf1.f;
    hp = (h0 >> 16) | h1;
    lp = (c.u >> 16) | (d.u & 0xFFFF0000u);
}

// ---------------------------------------------------------------------------
// W prep: pack Wq/Wk/Wv into MFMA B-frag order, bf16 hi/lo. (layout verified r3)
// ---------------------------------------------------------------------------
__global__ __launch_bounds__(256) void wprep_kernel(
    const float* __restrict__ Wq, const float* __restrict__ Wk,
    const float* __restrict__ Wv, unsigned short* __restrict__ Wf)
{
    int wv = blockIdx.x * 4 + (threadIdx.x >> 6);
    int l  = threadIdx.x & 63;
    const float* W; int C, kc32, ct;
    if (wv < 64)       { W = Wq; C = 32; kc32 = wv >> 1;  ct = wv & 1; }
    else if (wv < 128) { W = Wk; C = 32; int z = wv - 64;  kc32 = z >> 1; ct = z & 1; }
    else               { W = Wv; C = 64; int z = wv - 128; kc32 = z >> 2; ct = z & 3; }
    int k0 = kc32 * 32 + (l >> 4) * 8;
    int c  = ct * 16 + (l & 15);
    float x[8];
    #pragma unroll
    for (int j = 0; j < 8; ++j) x[j] = W[(size_t)(k0 + j) * C + c];
    unsigned hp[4], lp[4];
    #pragma unroll
    for (int j2 = 0; j2 < 4; ++j2) split2(x[2 * j2], x[2 * j2 + 1], hp[j2], lp[j2]);
    uint4 hv; hv.x = hp[0]; hv.y = hp[1]; hv.z = hp[2]; hv.w = hp[3];
    uint4 lv; lv.x = lp[0]; lv.y = lp[1]; lv.z = lp[2]; lv.w = lp[3];
    *(uint4*)&Wf[(size_t)wv * 1024 + l * 8]       = hv;
    *(uint4*)&Wf[(size_t)wv * 1024 + 512 + l * 8] = lv;
}

// ---------------------------------------------------------------------------
// Projections: register-direct A-frags, split-K x4 across 4 waves, LDS
// cross-wave reduction. grid 768 x 256. (unchanged, verified)
// ---------------------------------------------------------------------------
__global__ __launch_bounds__(256) void proj_mfma2_kernel(
    const float* __restrict__ Q, const float* __restrict__ K, const float* __restrict__ V,
    const unsigned short* __restrict__ Wf,
    float* __restrict__ Qt, float* __restrict__ Kt, unsigned short* __restrict__ VpT)
{
    __shared__ float red[4][64][16];   // [wave][lane][ct*4+r]  = 16 KB

    int gb = blockIdx.x;
    int job = gb >> 8, tile = gb & 255;
    int r0 = tile * 16;
    const float* X = (job == 0) ? Q : (job == 1) ? K : V;
    int ntct  = (job == 2) ? 4 : 2;
    int pbase = job << 6;
    int t = threadIdx.x, w = t >> 6, l = t & 63;
    int lrow = l & 15, lq = l >> 4;

    const float* xrow = &X[(size_t)(r0 + lrow) * DM + w * 256 + lq * 8];

    floatx4 acc[4];
    #pragma unroll
    for (int i = 0; i < 4; ++i) acc[i] = (floatx4){0.f, 0.f, 0.f, 0.f};

    #pragma unroll
    for (int s = 0; s < 8; ++s) {
        floatx4 g0 = *(const floatx4*)(xrow + s * 32);
        floatx4 g1 = *(const floatx4*)(xrow + s * 32 + 4);
        union { unsigned u[4]; shortx8 v; } ahi, alo;
        split2(g0.x, g0.y, ahi.u[0], alo.u[0]);
        split2(g0.z, g0.w, ahi.u[1], alo.u[1]);
        split2(g1.x, g1.y, ahi.u[2], alo.u[2]);
        split2(g1.z, g1.w, ahi.u[3], alo.u[3]);
        int kc32 = w * 8 + s;
        #pragma unroll
        for (int ct = 0; ct < 4; ++ct) {
            if (ct >= ntct) break;
            int p = pbase + kc32 * ntct + ct;
            const unsigned short* wp = &Wf[(size_t)p * 1024 + l * 8];
            shortx8 bhi = *(const shortx8*)wp;
            shortx8 blo = *(const shortx8*)(wp + 512);
            acc[ct] = __builtin_amdgcn_mfma_f32_16x16x32_bf16(ahi.v, bhi, acc[ct], 0, 0, 0);
            acc[ct] = __builtin_amdgcn_mfma_f32_16x16x32_bf16(ahi.v, blo, acc[ct], 0, 0, 0);
            acc[ct] = __builtin_amdgcn_mfma_f32_16x16x32_bf16(alo.v, bhi, acc[ct], 0, 0, 0);
        }
    }

    #pragma unroll
    for (int ct = 0; ct < 4; ++ct) {
        if (ct >= ntct) break;
        #pragma unroll
        for (int r = 0; r < 4; ++r) red[w][l][ct * 4 + r] = acc[ct][r];
    }
    __syncthreads();

    int row = r0 + lq * 4 + w;
    if (job < 2) {
        float* Y = (job == 0) ? Qt : Kt;
        #pragma unroll
        for (int ct = 0; ct < 2; ++ct) {
            float v = red[0][l][ct * 4 + w] + red[1][l][ct * 4 + w]
                    + red[2][l][ct * 4 + w] + red[3][l][ct * 4 + w];
            Y[(size_t)row * MBITS + ct * 16 + lrow] = v;
        }
    } else {
        int b = row >> 11, j = row & 2047;
        #pragma unroll
        for (int ct = 0; ct < 4; ++ct) {
            float v = red[0][l][ct * 4 + w] + red[1][l][ct * 4 + w]
                    + red[2][l][ct * 4 + w] + red[3][l][ct * 4 + w];
            VpT[(size_t)b * (DH * NB) + (size_t)(ct * 16 + lrow) * NB + j] = f32_to_bf16(v);
        }
    }
}

// ---------------------------------------------------------------------------
// Fused score + softmax + attn-write + PV pass.
// Grid (128, 2) x 1024 threads (16 waves), 1 block/CU, 148 KB LDS.
//
// __launch_bounds__(1024, 4): 16-wave block at 1 block/CU = 4 waves/SIMD ->
// VGPR cap 128 (r1 post-mortem: the bare (1024) default capped VGPRs at 64,
// spilling phase-1's ~90-reg working set to scratch -> 352 MB FETCH /
// 305 MB WRITE of spill traffic, 266 us. LDS already limits to 1 block/CU,
// so 4 waves/EU is the true occupancy; declare it.)
// ---------------------------------------------------------------------------
__global__ __launch_bounds__(1024, 4) void fused_score_out_kernel(
    const float* __restrict__ Qt, const float* __restrict__ Kt,
    const unsigned short* __restrict__ VpT, const float* __restrict__ temp,
    float* __restrict__ outp, float* __restrict__ attn)
{
    __shared__ unsigned short Elds[16][2056];    // 65792 B  unnormalized e (bf16)
    __shared__ unsigned short Vsb[2][64][256];   // 65536 B  V tile double buffer
    __shared__ float redsum[16][8];              //   512 B  per-wave row sums
    __shared__ float inv_s[16];                  //    64 B
    __shared__ float redC[16][64][4];            // 16384 B  cross-wave C reduce

    const int b  = blockIdx.y;
    const int i0 = blockIdx.x * 16;
    const int t  = threadIdx.x;
    const int w  = t >> 6, l = t & 63;
    const int wr = w & 1;              // row half (rows wr*8 .. wr*8+7)
    const int wj = w >> 1;             // j octant
    const int jb = wj * 256 + l * 4;   // first of this lane's 4 j columns

    const float tv = temp[0];
    const float c2 = -(1.0f / log1pf(__expf(tv))) * 1.44269504088896340736f;

    const float* Krow = &Kt[(size_t)(b * NB + jb) * MBITS];
    const float* Qrow = &Qt[(size_t)(b * NB + i0 + wr * 8) * MBITS];

    // ---- Phase 1: tropical min-plus ------------------------------------
    float m[8][4];
    #pragma unroll
    for (int r = 0; r < 8; ++r)
        #pragma unroll
        for (int jj = 0; jj < 4; ++jj) m[r][jj] = 1e30f;

    #pragma unroll
    for (int k4 = 0; k4 < 8; ++k4) {
        floatx4 kk[4];
        #pragma unroll
        for (int jj = 0; jj < 4; ++jj)
            kk[jj] = *(const floatx4*)&Krow[jj * MBITS + k4 * 4];
        #pragma unroll
        for (int r = 0; r < 8; ++r) {
            floatx4 q = *(const floatx4*)&Qrow[r * MBITS + k4 * 4];  // wave-uniform, L1-hot
            #pragma unroll
            for (int jj = 0; jj < 4; ++jj) {
                float a0 = q.x + kk[jj].x;
                float a1 = q.y + kk[jj].y;
                float a2 = q.z + kk[jj].z;
                float a3 = q.w + kk[jj].w;
                m[r][jj] = fminf(fminf(m[r][jj], fminf(a0, a1)), fminf(a2, a3));
            }
        }
    }

    // e = exp2(c2*m); write bf16 to Elds; per-row wave-reduced sums
    #pragma unroll
    for (int r = 0; r < 8; ++r) {
        float e0 = exp2f(c2 * m[r][0]);
        float e1 = exp2f(c2 * m[r][1]);
        float e2 = exp2f(c2 * m[r][2]);
        float e3 = exp2f(c2 * m[r][3]);
        uint2 pk;
        pk.x = (unsigned)f32_to_bf16(e0) | ((unsigned)f32_to_bf16(e1) << 16);
        pk.y = (unsigned)f32_to_bf16(e2) | ((unsigned)f32_to_bf16(e3) << 16);
        *(uint2*)&Elds[wr * 8 + r][jb] = pk;
        float s = (e0 + e1) + (e2 + e3);
        #pragma unroll
        for (int off = 1; off < 64; off <<= 1) s += __shfl_xor(s, off, 64);
        if (l == 0) redsum[w][r] = s;
    }
    __syncthreads();

    // inv_s: row i gets contributions from waves w with (w&1)==(i>>3)
    if (t < 16) {
        float s = 0.f;
        #pragma unroll
        for (int g = 0; g < 8; ++g) s += redsum[(t >> 3) + 2 * g][t & 7];
        inv_s[t] = 1.0f / s;
    }

    // stage V chunk 0 into buffer 0 (same layout/swizzle as verified kernel)
    const int sh = t >> 5, sc = t & 31;
    {
        uint4 g0 = *(const uint4*)&VpT[(size_t)b * (DH * NB) + (size_t)sh * NB + sc * 8];
        uint4 g1 = *(const uint4*)&VpT[(size_t)b * (DH * NB) + (size_t)(sh + 32) * NB + sc * 8];
        *(uint4*)&Vsb[0][sh][(sc ^ (sh & 31)) * 8]             = g0;
        *(uint4*)&Vsb[0][sh + 32][(sc ^ ((sh + 32) & 31)) * 8] = g1;
    }
    __syncthreads();

    // ---- Phase 2: normalize + attn write + PV MFMA ----------------------
    const int mrow = l & 15, q4 = l >> 4;
    const int hh  = (w & 3) * 16 + mrow;   // output head column this wave owns
    const int kg  = w >> 2;                // k-split group (0..3)
    const int vsw = hh & 31;
    const float iv = inv_s[w];             // this wave normalizes attn row w
    floatx4 acc = {0.f, 0.f, 0.f, 0.f};
    int pb = 0;

    for (int jc2 = 0; jc2 < 8; ++jc2) {
        // T14: issue next-tile loads early, write to LDS late
        uint4 g0, g1;
        if (jc2 < 7) {
            g0 = *(const uint4*)&VpT[(size_t)b * (DH * NB) + (size_t)sh * NB + (jc2 + 1) * 256 + sc * 8];
            g1 = *(const uint4*)&VpT[(size_t)b * (DH * NB) + (size_t)(sh + 32) * NB + (jc2 + 1) * 256 + sc * 8];
        }
        // MFMA: this wave's 2 k-steps of this chunk (accumulate across chunks)
        #pragma unroll
        for (int t2 = 0; t2 < 2; ++t2) {
            int ks = kg * 2 + t2;
            shortx8 a = *(const shortx8*)&Elds[mrow][jc2 * 256 + ks * 32 + q4 * 8];
            int c = ks * 4 + q4;
            shortx8 bf = *(const shortx8*)&Vsb[pb][hh][(c ^ vsw) * 8];
            acc = __builtin_amdgcn_mfma_f32_16x16x32_bf16(a, bf, acc, 0, 0, 0);
        }
        // normalize + write attn (wave w owns row w; 1 KB contiguous per wave)
        {
            uint2 pk = *(const uint2*)&Elds[w][jc2 * 256 + l * 4];
            union { unsigned u; float f; } x0, x1, x2, x3;
            x0.u = pk.x << 16; x1.u = pk.x & 0xFFFF0000u;
            x2.u = pk.y << 16; x3.u = pk.y & 0xFFFF0000u;
            floatx4 o;
            o.x = x0.f * iv; o.y = x1.f * iv; o.z = x2.f * iv; o.w = x3.f * iv;
            *(floatx4*)&attn[(size_t)(b * NB + i0 + w) * 2048 + jc2 * 256 + l * 4] = o;
        }
        if (jc2 < 7) {
            *(uint4*)&Vsb[pb ^ 1][sh][(sc ^ (sh & 31)) * 8]             = g0;
            *(uint4*)&Vsb[pb ^ 1][sh + 32][(sc ^ ((sh + 32) & 31)) * 8] = g1;
        }
        __syncthreads();
        pb ^= 1;
    }

    // cross-wave reduce the 4 k-split partial accumulators, write out
    *(floatx4*)&redC[w][l][0] = acc;
    __syncthreads();
    if (w < 4) {
        floatx4 v0 = *(const floatx4*)&redC[w][l][0];
        floatx4 v1 = *(const floatx4*)&redC[w + 4][l][0];
        floatx4 v2 = *(const floatx4*)&redC[w + 8][l][0];
        floatx4 v3 = *(const floatx4*)&redC[w + 12][l][0];
        #pragma unroll
        for (int r = 0; r < 4; ++r) {
            int irow = q4 * 4 + r;
            float v = (v0[r] + v1[r]) + (v2[r] + v3[r]);
            outp[(size_t)(b * NB + i0 + irow) * DH + w * 16 + mrow] = v * inv_s[irow];
        }
    }
}

// ---------------------------------------------------------------------------
extern "C" void kernel_launch(void* const* d_in, const int* in_sizes, int n_in,
                              void* d_out, int out_size, void* d_ws, size_t ws_size,
                              hipStream_t stream) {
    (void)in_sizes; (void)n_in; (void)out_size; (void)ws_size;
    const float* Q    = (const float*)d_in[0];
    const float* K    = (const float*)d_in[1];
    const float* V    = (const float*)d_in[2];
    const float* Wq   = (const float*)d_in[3];
    const float* Wk   = (const float*)d_in[4];
    const float* Wv   = (const float*)d_in[5];
    const float* temp = (const float*)d_in[6];

    float* outp = (float*)d_out;                 // [2][2048][64]
    float* attn = outp + 2 * 2048 * 64;          // [2][2048][2048]

    char* ws = (char*)d_ws;
    float*          Qt  = (float*)(ws);                       // 512 KB
    float*          Kt  = (float*)(ws + 524288);              // 512 KB
    unsigned short* Wf  = (unsigned short*)(ws + 1179648);    // 512 KB
    unsigned short* VpT = (unsigned short*)(ws + 1703936);    // 512 KB

    wprep_kernel<<<64, 256, 0, stream>>>(Wq, Wk, Wv, Wf);
    proj_mfma2_kernel<<<768, 256, 0, stream>>>(Q, K, V, Wf, Qt, Kt, VpT);
    fused_score_out_kernel<<<dim3(128, 2), 1024, 0, stream>>>(Qt, Kt, VpT, temp, outp, attn);
}

// Round 4
// 269.842 us; speedup vs baseline: 1.2768x; 1.2629x over previous
//
#include <hip/hip_runtime.h>
#include <math.h>

// Problem constants (B=2, N=M=2048, d_model=1024, m_bits=32, d_head=64)
#define DM 1024
#define NB 2048
#define MBITS 32
#define DH 64

typedef __attribute__((ext_vector_type(4))) float floatx4;
typedef __attribute__((ext_vector_type(8))) short shortx8;

__device__ __forceinline__ unsigned short f32_to_bf16(float f) {
    union { float f; unsigned u; } v; v.f = f;
    unsigned r = v.u + 0x7FFF + ((v.u >> 16) & 1);   // RNE
    return (unsigned short)(r >> 16);
}

// hi/lo truncation split of two f32 -> packed bf16x2 (el0 low, el1 high)
__device__ __forceinline__ void split2(float x0, float x1, unsigned& hp, unsigned& lp) {
    union { float f; unsigned u; } a, b; a.f = x0; b.f = x1;
    unsigned h0 = a.u & 0xFFFF0000u, h1 = b.u & 0xFFFF0000u;
    union { unsigned u; float f; } hf0, hf1; hf0.u = h0; hf1.u = h1;
    union { float f; unsigned u; } c, d;
    c.f = x0 - hf0.f;   // exact (Sterbenz)
    d.f = x1 - hf1.f;
    hp = (h0 >> 16) | h1;
    lp = (c.u >> 16) | (d.u & 0xFFFF0000u);
}

// ---------------------------------------------------------------------------
// W prep: pack Wq/Wk/Wv into MFMA B-frag order, bf16 hi/lo. (layout verified r3)
// ---------------------------------------------------------------------------
__global__ __launch_bounds__(256) void wprep_kernel(
    const float* __restrict__ Wq, const float* __restrict__ Wk,
    const float* __restrict__ Wv, unsigned short* __restrict__ Wf)
{
    int wv = blockIdx.x * 4 + (threadIdx.x >> 6);
    int l  = threadIdx.x & 63;
    const float* W; int C, kc32, ct;
    if (wv < 64)       { W = Wq; C = 32; kc32 = wv >> 1;  ct = wv & 1; }
    else if (wv < 128) { W = Wk; C = 32; int z = wv - 64;  kc32 = z >> 1; ct = z & 1; }
    else               { W = Wv; C = 64; int z = wv - 128; kc32 = z >> 2; ct = z & 3; }
    int k0 = kc32 * 32 + (l >> 4) * 8;
    int c  = ct * 16 + (l & 15);
    float x[8];
    #pragma unroll
    for (int j = 0; j < 8; ++j) x[j] = W[(size_t)(k0 + j) * C + c];
    unsigned hp[4], lp[4];
    #pragma unroll
    for (int j2 = 0; j2 < 4; ++j2) split2(x[2 * j2], x[2 * j2 + 1], hp[j2], lp[j2]);
    uint4 hv; hv.x = hp[0]; hv.y = hp[1]; hv.z = hp[2]; hv.w = hp[3];
    uint4 lv; lv.x = lp[0]; lv.y = lp[1]; lv.z = lp[2]; lv.w = lp[3];
    *(uint4*)&Wf[(size_t)wv * 1024 + l * 8]       = hv;
    *(uint4*)&Wf[(size_t)wv * 1024 + 512 + l * 8] = lv;
}

// ---------------------------------------------------------------------------
// Projections: register-direct A-frags, split-K x4 across 4 waves, LDS
// cross-wave reduction. grid 768 x 256. (unchanged, verified)
// ---------------------------------------------------------------------------
__global__ __launch_bounds__(256) void proj_mfma2_kernel(
    const float* __restrict__ Q, const float* __restrict__ K, const float* __restrict__ V,
    const unsigned short* __restrict__ Wf,
    float* __restrict__ Qt, float* __restrict__ Kt, unsigned short* __restrict__ VpT)
{
    __shared__ float red[4][64][16];   // [wave][lane][ct*4+r]  = 16 KB

    int gb = blockIdx.x;
    int job = gb >> 8, tile = gb & 255;
    int r0 = tile * 16;
    const float* X = (job == 0) ? Q : (job == 1) ? K : V;
    int ntct  = (job == 2) ? 4 : 2;
    int pbase = job << 6;
    int t = threadIdx.x, w = t >> 6, l = t & 63;
    int lrow = l & 15, lq = l >> 4;

    const float* xrow = &X[(size_t)(r0 + lrow) * DM + w * 256 + lq * 8];

    floatx4 acc[4];
    #pragma unroll
    for (int i = 0; i < 4; ++i) acc[i] = (floatx4){0.f, 0.f, 0.f, 0.f};

    #pragma unroll
    for (int s = 0; s < 8; ++s) {
        floatx4 g0 = *(const floatx4*)(xrow + s * 32);
        floatx4 g1 = *(const floatx4*)(xrow + s * 32 + 4);
        union { unsigned u[4]; shortx8 v; } ahi, alo;
        split2(g0.x, g0.y, ahi.u[0], alo.u[0]);
        split2(g0.z, g0.w, ahi.u[1], alo.u[1]);
        split2(g1.x, g1.y, ahi.u[2], alo.u[2]);
        split2(g1.z, g1.w, ahi.u[3], alo.u[3]);
        int kc32 = w * 8 + s;
        #pragma unroll
        for (int ct = 0; ct < 4; ++ct) {
            if (ct >= ntct) break;
            int p = pbase + kc32 * ntct + ct;
            const unsigned short* wp = &Wf[(size_t)p * 1024 + l * 8];
            shortx8 bhi = *(const shortx8*)wp;
            shortx8 blo = *(const shortx8*)(wp + 512);
            acc[ct] = __builtin_amdgcn_mfma_f32_16x16x32_bf16(ahi.v, bhi, acc[ct], 0, 0, 0);
            acc[ct] = __builtin_amdgcn_mfma_f32_16x16x32_bf16(ahi.v, blo, acc[ct], 0, 0, 0);
            acc[ct] = __builtin_amdgcn_mfma_f32_16x16x32_bf16(alo.v, bhi, acc[ct], 0, 0, 0);
        }
    }

    #pragma unroll
    for (int ct = 0; ct < 4; ++ct) {
        if (ct >= ntct) break;
        #pragma unroll
        for (int r = 0; r < 4; ++r) red[w][l][ct * 4 + r] = acc[ct][r];
    }
    __syncthreads();

    int row = r0 + lq * 4 + w;
    if (job < 2) {
        float* Y = (job == 0) ? Qt : Kt;
        #pragma unroll
        for (int ct = 0; ct < 2; ++ct) {
            float v = red[0][l][ct * 4 + w] + red[1][l][ct * 4 + w]
                    + red[2][l][ct * 4 + w] + red[3][l][ct * 4 + w];
            Y[(size_t)row * MBITS + ct * 16 + lrow] = v;
        }
    } else {
        int b = row >> 11, j = row & 2047;
        #pragma unroll
        for (int ct = 0; ct < 4; ++ct) {
            float v = red[0][l][ct * 4 + w] + red[1][l][ct * 4 + w]
                    + red[2][l][ct * 4 + w] + red[3][l][ct * 4 + w];
            VpT[(size_t)b * (DH * NB) + (size_t)(ct * 16 + lrow) * NB + j] = f32_to_bf16(v);
        }
    }
}

// ---------------------------------------------------------------------------
// Fused score + softmax + attn-write + PV pass.
// Grid (128, 2) x 1024 threads (16 waves), 1 block/CU, 148 KB LDS.
//
// r3 post-mortem: the compiler budget is 64 arch VGPRs for this kernel
// regardless of __launch_bounds__ min-waves (measured: VGPR_Count=64 in r1
// AND r3; spill signature 347 MB FETCH / 305 MB WRITE = m[8][4] in scratch).
// Fix: phase 1 runs as TWO sequential 4-row halves (#pragma unroll 1) so the
// live set (m[4][4]=16 + kk=16 + q + addr ~ 50 regs) fits 64. Kt is swept
// twice per block (+256 KB L2-resident reads, ~negligible).
// ---------------------------------------------------------------------------
__global__ __launch_bounds__(1024, 4) void fused_score_out_kernel(
    const float* __restrict__ Qt, const float* __restrict__ Kt,
    const unsigned short* __restrict__ VpT, const float* __restrict__ temp,
    float* __restrict__ outp, float* __restrict__ attn)
{
    __shared__ unsigned short Elds[16][2056];    // 65792 B  unnormalized e (bf16)
    __shared__ unsigned short Vsb[2][64][256];   // 65536 B  V tile double buffer
    __shared__ float redsum[16][8];              //   512 B  per-wave row sums
    __shared__ float inv_s[16];                  //    64 B
    __shared__ float redC[16][64][4];            // 16384 B  cross-wave C reduce

    const int b  = blockIdx.y;
    const int i0 = blockIdx.x * 16;
    const int t  = threadIdx.x;
    const int w  = t >> 6, l = t & 63;
    const int wr = w & 1;              // row half (rows wr*8 .. wr*8+7)
    const int wj = w >> 1;             // j octant
    const int jb = wj * 256 + l * 4;   // first of this lane's 4 j columns

    const float tv = temp[0];
    const float c2 = -(1.0f / log1pf(__expf(tv))) * 1.44269504088896340736f;

    const float* Krow = &Kt[(size_t)(b * NB + jb) * MBITS];
    const float* Qrow = &Qt[(size_t)(b * NB + i0 + wr * 8) * MBITS];

    // ---- Phase 1: tropical min-plus, two sequential 4-row halves --------
    #pragma unroll 1
    for (int half = 0; half < 2; ++half) {
        float m[4][4];
        #pragma unroll
        for (int r = 0; r < 4; ++r)
            #pragma unroll
            for (int jj = 0; jj < 4; ++jj) m[r][jj] = 1e30f;

        const float* Qh = Qrow + (size_t)half * 4 * MBITS;

        #pragma unroll
        for (int k4 = 0; k4 < 8; ++k4) {
            floatx4 kk[4];
            #pragma unroll
            for (int jj = 0; jj < 4; ++jj)
                kk[jj] = *(const floatx4*)&Krow[jj * MBITS + k4 * 4];
            #pragma unroll
            for (int r = 0; r < 4; ++r) {
                floatx4 q = *(const floatx4*)&Qh[r * MBITS + k4 * 4];  // wave-uniform, L1-hot
                #pragma unroll
                for (int jj = 0; jj < 4; ++jj) {
                    float a0 = q.x + kk[jj].x;
                    float a1 = q.y + kk[jj].y;
                    float a2 = q.z + kk[jj].z;
                    float a3 = q.w + kk[jj].w;
                    m[r][jj] = fminf(fminf(m[r][jj], fminf(a0, a1)), fminf(a2, a3));
                }
            }
        }

        // e = exp2(c2*m); write bf16 to Elds; per-row wave-reduced sums
        #pragma unroll
        for (int r = 0; r < 4; ++r) {
            int rr = half * 4 + r;
            float e0 = exp2f(c2 * m[r][0]);
            float e1 = exp2f(c2 * m[r][1]);
            float e2 = exp2f(c2 * m[r][2]);
            float e3 = exp2f(c2 * m[r][3]);
            uint2 pk;
            pk.x = (unsigned)f32_to_bf16(e0) | ((unsigned)f32_to_bf16(e1) << 16);
            pk.y = (unsigned)f32_to_bf16(e2) | ((unsigned)f32_to_bf16(e3) << 16);
            *(uint2*)&Elds[wr * 8 + rr][jb] = pk;
            float s = (e0 + e1) + (e2 + e3);
            #pragma unroll
            for (int off = 1; off < 64; off <<= 1) s += __shfl_xor(s, off, 64);
            if (l == 0) redsum[w][rr] = s;
        }
    }
    __syncthreads();

    // inv_s: row i gets contributions from waves w with (w&1)==(i>>3)
    if (t < 16) {
        float s = 0.f;
        #pragma unroll
        for (int g = 0; g < 8; ++g) s += redsum[(t >> 3) + 2 * g][t & 7];
        inv_s[t] = 1.0f / s;
    }

    // stage V chunk 0 into buffer 0 (same layout/swizzle as verified kernel)
    const int sh = t >> 5, sc = t & 31;
    {
        uint4 g0 = *(const uint4*)&VpT[(size_t)b * (DH * NB) + (size_t)sh * NB + sc * 8];
        uint4 g1 = *(const uint4*)&VpT[(size_t)b * (DH * NB) + (size_t)(sh + 32) * NB + sc * 8];
        *(uint4*)&Vsb[0][sh][(sc ^ (sh & 31)) * 8]             = g0;
        *(uint4*)&Vsb[0][sh + 32][(sc ^ ((sh + 32) & 31)) * 8] = g1;
    }
    __syncthreads();

    // ---- Phase 2: normalize + attn write + PV MFMA ----------------------
    const int mrow = l & 15, q4 = l >> 4;
    const int hh  = (w & 3) * 16 + mrow;   // output head column this wave owns
    const int kg  = w >> 2;                // k-split group (0..3)
    const int vsw = hh & 31;
    const float iv = inv_s[w];             // this wave normalizes attn row w
    floatx4 acc = {0.f, 0.f, 0.f, 0.f};
    int pb = 0;

    for (int jc2 = 0; jc2 < 8; ++jc2) {
        // T14: issue next-tile loads early, write to LDS late
        uint4 g0, g1;
        if (jc2 < 7) {
            g0 = *(const uint4*)&VpT[(size_t)b * (DH * NB) + (size_t)sh * NB + (jc2 + 1) * 256 + sc * 8];
            g1 = *(const uint4*)&VpT[(size_t)b * (DH * NB) + (size_t)(sh + 32) * NB + (jc2 + 1) * 256 + sc * 8];
        }
        // MFMA: this wave's 2 k-steps of this chunk (accumulate across chunks)
        #pragma unroll
        for (int t2 = 0; t2 < 2; ++t2) {
            int ks = kg * 2 + t2;
            shortx8 a = *(const shortx8*)&Elds[mrow][jc2 * 256 + ks * 32 + q4 * 8];
            int c = ks * 4 + q4;
            shortx8 bf = *(const shortx8*)&Vsb[pb][hh][(c ^ vsw) * 8];
            acc = __builtin_amdgcn_mfma_f32_16x16x32_bf16(a, bf, acc, 0, 0, 0);
        }
        // normalize + write attn (wave w owns row w; 1 KB contiguous per wave)
        {
            uint2 pk = *(const uint2*)&Elds[w][jc2 * 256 + l * 4];
            union { unsigned u; float f; } x0, x1, x2, x3;
            x0.u = pk.x << 16; x1.u = pk.x & 0xFFFF0000u;
            x2.u = pk.y << 16; x3.u = pk.y & 0xFFFF0000u;
            floatx4 o;
            o.x = x0.f * iv; o.y = x1.f * iv; o.z = x2.f * iv; o.w = x3.f * iv;
            *(floatx4*)&attn[(size_t)(b * NB + i0 + w) * 2048 + jc2 * 256 + l * 4] = o;
        }
        if (jc2 < 7) {
            *(uint4*)&Vsb[pb ^ 1][sh][(sc ^ (sh & 31)) * 8]             = g0;
            *(uint4*)&Vsb[pb ^ 1][sh + 32][(sc ^ ((sh + 32) & 31)) * 8] = g1;
        }
        __syncthreads();
        pb ^= 1;
    }

    // cross-wave reduce the 4 k-split partial accumulators, write out
    *(floatx4*)&redC[w][l][0] = acc;
    __syncthreads();
    if (w < 4) {
        floatx4 v0 = *(const floatx4*)&redC[w][l][0];
        floatx4 v1 = *(const floatx4*)&redC[w + 4][l][0];
        floatx4 v2 = *(const floatx4*)&redC[w + 8][l][0];
        floatx4 v3 = *(const floatx4*)&redC[w + 12][l][0];
        #pragma unroll
        for (int r = 0; r < 4; ++r) {
            int irow = q4 * 4 + r;
            float v = (v0[r] + v1[r]) + (v2[r] + v3[r]);
            outp[(size_t)(b * NB + i0 + irow) * DH + w * 16 + mrow] = v * inv_s[irow];
        }
    }
}

// ---------------------------------------------------------------------------
extern "C" void kernel_launch(void* const* d_in, const int* in_sizes, int n_in,
                              void* d_out, int out_size, void* d_ws, size_t ws_size,
                              hipStream_t stream) {
    (void)in_sizes; (void)n_in; (void)out_size; (void)ws_size;
    const float* Q    = (const float*)d_in[0];
    const float* K    = (const float*)d_in[1];
    const float* V    = (const float*)d_in[2];
    const float* Wq   = (const float*)d_in[3];
    const float* Wk   = (const float*)d_in[4];
    const float* Wv   = (const float*)d_in[5];
    const float* temp = (const float*)d_in[6];

    float* outp = (float*)d_out;                 // [2][2048][64]
    float* attn = outp + 2 * 2048 * 64;          // [2][2048][2048]

    char* ws = (char*)d_ws;
    float*          Qt  = (float*)(ws);                       // 512 KB
    float*          Kt  = (float*)(ws + 524288);              // 512 KB
    unsigned short* Wf  = (unsigned short*)(ws + 1179648);    // 512 KB
    unsigned short* VpT = (unsigned short*)(ws + 1703936);    // 512 KB

    wprep_kernel<<<64, 256, 0, stream>>>(Wq, Wk, Wv, Wf);
    proj_mfma2_kernel<<<768, 256, 0, stream>>>(Q, K, V, Wf, Qt, Kt, VpT);
    fused_score_out_kernel<<<dim3(128, 2), 1024, 0, stream>>>(Qt, Kt, VpT, temp, outp, attn);
}

// Round 5
// 151.430 us; speedup vs baseline: 2.2752x; 1.7820x over previous
//
#include <hip/hip_runtime.h>
#include <math.h>

// Problem constants (B=2, N=M=2048, d_model=1024, m_bits=32, d_head=64)
#define DM 1024
#define NB 2048
#define MBITS 32
#define DH 64

typedef __attribute__((ext_vector_type(4))) float floatx4;
typedef __attribute__((ext_vector_type(8))) short shortx8;

__device__ __forceinline__ unsigned short f32_to_bf16(float f) {
    union { float f; unsigned u; } v; v.f = f;
    unsigned r = v.u + 0x7FFF + ((v.u >> 16) & 1);   // RNE
    return (unsigned short)(r >> 16);
}

// hi/lo truncation split of two f32 -> packed bf16x2 (el0 low, el1 high)
__device__ __forceinline__ void split2(float x0, float x1, unsigned& hp, unsigned& lp) {
    union { float f; unsigned u; } a, b; a.f = x0; b.f = x1;
    unsigned h0 = a.u & 0xFFFF0000u, h1 = b.u & 0xFFFF0000u;
    union { unsigned u; float f; } hf0, hf1; hf0.u = h0; hf1.u = h1;
    union { float f; unsigned u; } c, d;
    c.f = x0 - hf0.f;   // exact (Sterbenz)
    d.f = x1 - hf1.f;
    hp = (h0 >> 16) | h1;
    lp = (c.u >> 16) | (d.u & 0xFFFF0000u);
}

// ---------------------------------------------------------------------------
// W prep: pack Wq/Wk/Wv into MFMA B-frag order, bf16 hi/lo. (layout verified r3)
// ---------------------------------------------------------------------------
__global__ __launch_bounds__(256) void wprep_kernel(
    const float* __restrict__ Wq, const float* __restrict__ Wk,
    const float* __restrict__ Wv, unsigned short* __restrict__ Wf)
{
    int wv = blockIdx.x * 4 + (threadIdx.x >> 6);
    int l  = threadIdx.x & 63;
    const float* W; int C, kc32, ct;
    if (wv < 64)       { W = Wq; C = 32; kc32 = wv >> 1;  ct = wv & 1; }
    else if (wv < 128) { W = Wk; C = 32; int z = wv - 64;  kc32 = z >> 1; ct = z & 1; }
    else               { W = Wv; C = 64; int z = wv - 128; kc32 = z >> 2; ct = z & 3; }
    int k0 = kc32 * 32 + (l >> 4) * 8;
    int c  = ct * 16 + (l & 15);
    float x[8];
    #pragma unroll
    for (int j = 0; j < 8; ++j) x[j] = W[(size_t)(k0 + j) * C + c];
    unsigned hp[4], lp[4];
    #pragma unroll
    for (int j2 = 0; j2 < 4; ++j2) split2(x[2 * j2], x[2 * j2 + 1], hp[j2], lp[j2]);
    uint4 hv; hv.x = hp[0]; hv.y = hp[1]; hv.z = hp[2]; hv.w = hp[3];
    uint4 lv; lv.x = lp[0]; lv.y = lp[1]; lv.z = lp[2]; lv.w = lp[3];
    *(uint4*)&Wf[(size_t)wv * 1024 + l * 8]       = hv;
    *(uint4*)&Wf[(size_t)wv * 1024 + 512 + l * 8] = lv;
}

// ---------------------------------------------------------------------------
// Projections: register-direct A-frags, split-K x4 across 4 waves, LDS
// cross-wave reduction. grid 768 x 256.
// r5 change: job 1 now writes K-tropical TRANSPOSED: KtT[b][k=32][j=2048] f32,
// so the fused kernel's K reads can be lane-consecutive (coalesced). Within a
// block the 16 j values per k are contiguous (r0..r0+15) -> full 64B lines.
// ---------------------------------------------------------------------------
__global__ __launch_bounds__(256) void proj_mfma2_kernel(
    const float* __restrict__ Q, const float* __restrict__ K, const float* __restrict__ V,
    const unsigned short* __restrict__ Wf,
    float* __restrict__ Qt, float* __restrict__ KtT, unsigned short* __restrict__ VpT)
{
    __shared__ float red[4][64][16];   // [wave][lane][ct*4+r]  = 16 KB

    int gb = blockIdx.x;
    int job = gb >> 8, tile = gb & 255;
    int r0 = tile * 16;
    const float* X = (job == 0) ? Q : (job == 1) ? K : V;
    int ntct  = (job == 2) ? 4 : 2;
    int pbase = job << 6;
    int t = threadIdx.x, w = t >> 6, l = t & 63;
    int lrow = l & 15, lq = l >> 4;

    const float* xrow = &X[(size_t)(r0 + lrow) * DM + w * 256 + lq * 8];

    floatx4 acc[4];
    #pragma unroll
    for (int i = 0; i < 4; ++i) acc[i] = (floatx4){0.f, 0.f, 0.f, 0.f};

    #pragma unroll
    for (int s = 0; s < 8; ++s) {
        floatx4 g0 = *(const floatx4*)(xrow + s * 32);
        floatx4 g1 = *(const floatx4*)(xrow + s * 32 + 4);
        union { unsigned u[4]; shortx8 v; } ahi, alo;
        split2(g0.x, g0.y, ahi.u[0], alo.u[0]);
        split2(g0.z, g0.w, ahi.u[1], alo.u[1]);
        split2(g1.x, g1.y, ahi.u[2], alo.u[2]);
        split2(g1.z, g1.w, ahi.u[3], alo.u[3]);
        int kc32 = w * 8 + s;
        #pragma unroll
        for (int ct = 0; ct < 4; ++ct) {
            if (ct >= ntct) break;
            int p = pbase + kc32 * ntct + ct;
            const unsigned short* wp = &Wf[(size_t)p * 1024 + l * 8];
            shortx8 bhi = *(const shortx8*)wp;
            shortx8 blo = *(const shortx8*)(wp + 512);
            acc[ct] = __builtin_amdgcn_mfma_f32_16x16x32_bf16(ahi.v, bhi, acc[ct], 0, 0, 0);
            acc[ct] = __builtin_amdgcn_mfma_f32_16x16x32_bf16(ahi.v, blo, acc[ct], 0, 0, 0);
            acc[ct] = __builtin_amdgcn_mfma_f32_16x16x32_bf16(alo.v, bhi, acc[ct], 0, 0, 0);
        }
    }

    #pragma unroll
    for (int ct = 0; ct < 4; ++ct) {
        if (ct >= ntct) break;
        #pragma unroll
        for (int r = 0; r < 4; ++r) red[w][l][ct * 4 + r] = acc[ct][r];
    }
    __syncthreads();

    int row = r0 + lq * 4 + w;
    if (job == 0) {
        #pragma unroll
        for (int ct = 0; ct < 2; ++ct) {
            float v = red[0][l][ct * 4 + w] + red[1][l][ct * 4 + w]
                    + red[2][l][ct * 4 + w] + red[3][l][ct * 4 + w];
            Qt[(size_t)row * MBITS + ct * 16 + lrow] = v;
        }
    } else if (job == 1) {
        int bb = row >> 11, j = row & 2047;
        #pragma unroll
        for (int ct = 0; ct < 2; ++ct) {
            float v = red[0][l][ct * 4 + w] + red[1][l][ct * 4 + w]
                    + red[2][l][ct * 4 + w] + red[3][l][ct * 4 + w];
            KtT[(size_t)bb * (MBITS * NB) + (size_t)(ct * 16 + lrow) * NB + j] = v;
        }
    } else {
        int bb = row >> 11, j = row & 2047;
        #pragma unroll
        for (int ct = 0; ct < 4; ++ct) {
            float v = red[0][l][ct * 4 + w] + red[1][l][ct * 4 + w]
                    + red[2][l][ct * 4 + w] + red[3][l][ct * 4 + w];
            VpT[(size_t)bb * (DH * NB) + (size_t)(ct * 16 + lrow) * NB + j] = f32_to_bf16(v);
        }
    }
}

// ---------------------------------------------------------------------------
// Fused score + softmax + attn-write + PV pass.
// Grid (128, 2) x 1024 threads (16 waves), 1 block/CU, ~145 KB LDS.
//
// r5: phase 1 rewritten for coalesced K reads + <=64-reg live set:
//   wave w: i-pair (w&7)*2, j-half (w>>3)*1024; lane: k-phase p=l>>4 covers
//   k=p*8..p*8+7, (l&15)*8 gives 8 CONSECUTIVE j -> 2x b128 global loads from
//   KtT, 16-lane groups fully contiguous (full cache-line use). m[2][8] +
//   q[2][8] in regs; cross-phase min via 2x shfl_xor. No barriers, no LDS
//   staging in phase 1. amdgpu_waves_per_eu(4,4) lifts the VGPR budget to 128
//   (r1-r4: allocator targeted 8 waves/EU -> 64 regs -> scratch spill;
//   launch_bounds' 2nd arg only sets the MIN waves/EU, not the max).
// ---------------------------------------------------------------------------
__global__ __attribute__((amdgpu_waves_per_eu(4, 4))) __launch_bounds__(1024)
void fused_score_out_kernel(
    const float* __restrict__ Qt, const float* __restrict__ KtT,
    const unsigned short* __restrict__ VpT, const float* __restrict__ temp,
    float* __restrict__ outp, float* __restrict__ attn)
{
    __shared__ unsigned short Elds[16][2056];    // 65792 B  unnormalized e (bf16)
    __shared__ unsigned short Vsb[2][64][256];   // 65536 B  V tile double buffer
    __shared__ float redsum2[16][2];             //   128 B  per-wave row sums
    __shared__ float inv_s[16];                  //    64 B
    __shared__ float redC[16][64][4];            // 16384 B  cross-wave C reduce

    const int b  = blockIdx.y;
    const int i0 = blockIdx.x * 16;
    const int t  = threadIdx.x;
    const int w  = t >> 6, l = t & 63;

    const float tv = temp[0];
    const float c2 = -(1.0f / log1pf(__expf(tv))) * 1.44269504088896340736f;

    // ---- Phase 1: tropical min-plus (coalesced KtT reads) ----------------
    {
        const int ip  = w & 7;        // i-pair: local rows ip*2, ip*2+1
        const int jhb = (w >> 3) * 1024;
        const int p   = l >> 4;       // k-phase: k = p*8 .. p*8+7
        const int l16 = l & 15;

        const float* Qbase = &Qt[(size_t)(b * NB + i0 + ip * 2) * MBITS + p * 8];
        floatx4 qa0 = *(const floatx4*)(Qbase);
        floatx4 qa1 = *(const floatx4*)(Qbase + 4);
        floatx4 qb0 = *(const floatx4*)(Qbase + MBITS);
        floatx4 qb1 = *(const floatx4*)(Qbase + MBITS + 4);

        const float* Kp = &KtT[(size_t)b * (MBITS * NB) + (size_t)(p * 8) * NB];
        float sacc0 = 0.f, sacc1 = 0.f;

        #pragma unroll 1
        for (int s = 0; s < 8; ++s) {
            const int j0 = jhb + s * 128 + l16 * 8;
            float m0[8], m1[8];
            #pragma unroll
            for (int jj = 0; jj < 8; ++jj) { m0[jj] = 1e30f; m1[jj] = 1e30f; }

            #pragma unroll
            for (int kp = 0; kp < 8; ++kp) {
                const float* kr = Kp + (size_t)kp * NB + j0;
                floatx4 k0 = *(const floatx4*)kr;
                floatx4 k1 = *(const floatx4*)(kr + 4);
                float qa = (kp < 4) ? qa0[kp] : qa1[kp - 4];
                float qb = (kp < 4) ? qb0[kp] : qb1[kp - 4];
                float kv[8] = {k0.x, k0.y, k0.z, k0.w, k1.x, k1.y, k1.z, k1.w};
                #pragma unroll
                for (int jj = 0; jj < 8; ++jj) {
                    m0[jj] = fminf(m0[jj], qa + kv[jj]);
                    m1[jj] = fminf(m1[jj], qb + kv[jj]);
                }
            }
            // merge the 4 k-phases (lanes l, l^16, l^32 share (i-pair, j-octet))
            #pragma unroll
            for (int jj = 0; jj < 8; ++jj) {
                m0[jj] = fminf(m0[jj], __shfl_xor(m0[jj], 16, 64));
                m0[jj] = fminf(m0[jj], __shfl_xor(m0[jj], 32, 64));
                m1[jj] = fminf(m1[jj], __shfl_xor(m1[jj], 16, 64));
                m1[jj] = fminf(m1[jj], __shfl_xor(m1[jj], 32, 64));
            }
            // e = exp2(c2*m), pack bf16, write Elds (phase-0 lanes), row sums
            float e0[8], e1[8];
            #pragma unroll
            for (int jj = 0; jj < 8; ++jj) {
                e0[jj] = exp2f(c2 * m0[jj]);
                e1[jj] = exp2f(c2 * m1[jj]);
            }
            uint4 u0, u1;
            u0.x = (unsigned)f32_to_bf16(e0[0]) | ((unsigned)f32_to_bf16(e0[1]) << 16);
            u0.y = (unsigned)f32_to_bf16(e0[2]) | ((unsigned)f32_to_bf16(e0[3]) << 16);
            u0.z = (unsigned)f32_to_bf16(e0[4]) | ((unsigned)f32_to_bf16(e0[5]) << 16);
            u0.w = (unsigned)f32_to_bf16(e0[6]) | ((unsigned)f32_to_bf16(e0[7]) << 16);
            u1.x = (unsigned)f32_to_bf16(e1[0]) | ((unsigned)f32_to_bf16(e1[1]) << 16);
            u1.y = (unsigned)f32_to_bf16(e1[2]) | ((unsigned)f32_to_bf16(e1[3]) << 16);
            u1.z = (unsigned)f32_to_bf16(e1[4]) | ((unsigned)f32_to_bf16(e1[5]) << 16);
            u1.w = (unsigned)f32_to_bf16(e1[6]) | ((unsigned)f32_to_bf16(e1[7]) << 16);
            if (l < 16) {
                *(uint4*)&Elds[ip * 2][j0]     = u0;
                *(uint4*)&Elds[ip * 2 + 1][j0] = u1;
            }
            float s0 = ((e0[0] + e0[1]) + (e0[2] + e0[3])) + ((e0[4] + e0[5]) + (e0[6] + e0[7]));
            float s1 = ((e1[0] + e1[1]) + (e1[2] + e1[3])) + ((e1[4] + e1[5]) + (e1[6] + e1[7]));
            #pragma unroll
            for (int off = 1; off < 16; off <<= 1) {
                s0 += __shfl_xor(s0, off, 64);
                s1 += __shfl_xor(s1, off, 64);
            }
            sacc0 += s0; sacc1 += s1;
        }
        if (l == 0) { redsum2[w][0] = sacc0; redsum2[w][1] = sacc1; }
    }
    __syncthreads();

    // inv_s: row i = pair (i>>1), parity (i&1); halves are waves ip and ip+8
    if (t < 16) {
        inv_s[t] = 1.0f / (redsum2[t >> 1][t & 1] + redsum2[8 + (t >> 1)][t & 1]);
    }

    // stage V chunk 0 into buffer 0 (same layout/swizzle as verified kernel)
    const int sh = t >> 5, sc = t & 31;
    {
        uint4 g0 = *(const uint4*)&VpT[(size_t)b * (DH * NB) + (size_t)sh * NB + sc * 8];
        uint4 g1 = *(const uint4*)&VpT[(size_t)b * (DH * NB) + (size_t)(sh + 32) * NB + sc * 8];
        *(uint4*)&Vsb[0][sh][(sc ^ (sh & 31)) * 8]             = g0;
        *(uint4*)&Vsb[0][sh + 32][(sc ^ ((sh + 32) & 31)) * 8] = g1;
    }
    __syncthreads();

    // ---- Phase 2: normalize + attn write + PV MFMA ----------------------
    const int mrow = l & 15, q4 = l >> 4;
    const int hh  = (w & 3) * 16 + mrow;   // output head column this wave owns
    const int kg  = w >> 2;                // k-split group (0..3)
    const int vsw = hh & 31;
    const float iv = inv_s[w];             // this wave normalizes attn row w
    floatx4 acc = {0.f, 0.f, 0.f, 0.f};
    int pb = 0;

    for (int jc2 = 0; jc2 < 8; ++jc2) {
        // T14: issue next-tile loads early, write to LDS late
        uint4 g0, g1;
        if (jc2 < 7) {
            g0 = *(const uint4*)&VpT[(size_t)b * (DH * NB) + (size_t)sh * NB + (jc2 + 1) * 256 + sc * 8];
            g1 = *(const uint4*)&VpT[(size_t)b * (DH * NB) + (size_t)(sh + 32) * NB + (jc2 + 1) * 256 + sc * 8];
        }
        // MFMA: this wave's 2 k-steps of this chunk (accumulate across chunks)
        #pragma unroll
        for (int t2 = 0; t2 < 2; ++t2) {
            int ks = kg * 2 + t2;
            shortx8 a = *(const shortx8*)&Elds[mrow][jc2 * 256 + ks * 32 + q4 * 8];
            int c = ks * 4 + q4;
            shortx8 bf = *(const shortx8*)&Vsb[pb][hh][(c ^ vsw) * 8];
            acc = __builtin_amdgcn_mfma_f32_16x16x32_bf16(a, bf, acc, 0, 0, 0);
        }
        // normalize + write attn (wave w owns row w; 1 KB contiguous per wave)
        {
            uint2 pk = *(const uint2*)&Elds[w][jc2 * 256 + l * 4];
            union { unsigned u; float f; } x0, x1, x2, x3;
            x0.u = pk.x << 16; x1.u = pk.x & 0xFFFF0000u;
            x2.u = pk.y << 16; x3.u = pk.y & 0xFFFF0000u;
            floatx4 o;
            o.x = x0.f * iv; o.y = x1.f * iv; o.z = x2.f * iv; o.w = x3.f * iv;
            *(floatx4*)&attn[(size_t)(b * NB + i0 + w) * 2048 + jc2 * 256 + l * 4] = o;
        }
        if (jc2 < 7) {
            *(uint4*)&Vsb[pb ^ 1][sh][(sc ^ (sh & 31)) * 8]             = g0;
            *(uint4*)&Vsb[pb ^ 1][sh + 32][(sc ^ ((sh + 32) & 31)) * 8] = g1;
        }
        __syncthreads();
        pb ^= 1;
    }

    // cross-wave reduce the 4 k-split partial accumulators, write out
    *(floatx4*)&redC[w][l][0] = acc;
    __syncthreads();
    if (w < 4) {
        floatx4 v0 = *(const floatx4*)&redC[w][l][0];
        floatx4 v1 = *(const floatx4*)&redC[w + 4][l][0];
        floatx4 v2 = *(const floatx4*)&redC[w + 8][l][0];
        floatx4 v3 = *(const floatx4*)&redC[w + 12][l][0];
        #pragma unroll
        for (int r = 0; r < 4; ++r) {
            int irow = q4 * 4 + r;
            float v = (v0[r] + v1[r]) + (v2[r] + v3[r]);
            outp[(size_t)(b * NB + i0 + irow) * DH + w * 16 + mrow] = v * inv_s[irow];
        }
    }
}

// ---------------------------------------------------------------------------
extern "C" void kernel_launch(void* const* d_in, const int* in_sizes, int n_in,
                              void* d_out, int out_size, void* d_ws, size_t ws_size,
                              hipStream_t stream) {
    (void)in_sizes; (void)n_in; (void)out_size; (void)ws_size;
    const float* Q    = (const float*)d_in[0];
    const float* K    = (const float*)d_in[1];
    const float* V    = (const float*)d_in[2];
    const float* Wq   = (const float*)d_in[3];
    const float* Wk   = (const float*)d_in[4];
    const float* Wv   = (const float*)d_in[5];
    const float* temp = (const float*)d_in[6];

    float* outp = (float*)d_out;                 // [2][2048][64]
    float* attn = outp + 2 * 2048 * 64;          // [2][2048][2048]

    char* ws = (char*)d_ws;
    float*          Qt  = (float*)(ws);                       // 512 KB
    float*          KtT = (float*)(ws + 524288);              // 512 KB  [2][32][2048]
    unsigned short* Wf  = (unsigned short*)(ws + 1179648);    // 512 KB
    unsigned short* VpT = (unsigned short*)(ws + 1703936);    // 512 KB

    wprep_kernel<<<64, 256, 0, stream>>>(Wq, Wk, Wv, Wf);
    proj_mfma2_kernel<<<768, 256, 0, stream>>>(Q, K, V, Wf, Qt, KtT, VpT);
    fused_score_out_kernel<<<dim3(128, 2), 1024, 0, stream>>>(Qt, KtT, VpT, temp, outp, attn);
}